// Round 7
// baseline (805.190 us; speedup 1.0000x reference)
//
#include <hip/hip_runtime.h>
#include <hip/hip_bf16.h>
#include <hip/hip_fp16.h>

// ---------------- problem constants (from reference) ----------------
// N = 100000 nodes, E = 1600000 edges, F_IN = 512, H1*C1 = 64, NUM_CLASSES = 40
#define F_IN 512
#define HC1 64          // 8 heads * 8 ch
#define NH1 8
#define NC 40
#define NEG_SLOPE 0.2f
#define SCAN_CHUNK 2048
#define RADIX_EPB 4096  // edges per block in scatter1
#define MAXNB 512       // max node buckets (256 nodes each)
#define BCAP 8192       // fixed bucket capacity (mean 4096, +64 sigma)

typedef short bf16x8 __attribute__((ext_vector_type(8)));
typedef float f32x4 __attribute__((ext_vector_type(4)));

static __device__ __forceinline__ unsigned short f2b(float f) {
    __hip_bfloat16 h = __float2bfloat16(f);      // RNE
    return *(unsigned short*)&h;
}
static __device__ __forceinline__ float b2f(unsigned short u) {
    union { unsigned int i; float f; } v;
    v.i = ((unsigned int)u) << 16;               // bf16 -> fp32 exact
    return v.f;
}
static __device__ __forceinline__ unsigned short f2h(float f) {
    __half h = __float2half(f);
    return *(unsigned short*)&h;
}
static __device__ __forceinline__ float h2f(unsigned short u) {
    __half h = *(__half*)&u;
    return __half2float(h);
}

__device__ __forceinline__ float lrelu(float e) { return e > 0.f ? e : NEG_SLOPE * e; }

// ---------------- one-shot param prep + edge dtype detect (fused) ----------------
__global__ void prep(const float* __restrict__ W1, const float* __restrict__ W2,
                     const float* __restrict__ a_s2, const float* __restrict__ a_d2,
                     const int* __restrict__ ei,
                     unsigned short* __restrict__ wst, float* __restrict__ ws2,
                     float* __restrict__ wd2, int* __restrict__ flag) {
    if (blockIdx.x == 16) {
        __shared__ int found;
        if (threadIdx.x == 0) found = 0;
        __syncthreads();
        for (int i = threadIdx.x; i < 4096; i += 256) {
            if (ei[2 * i + 1] != 0) atomicOr(&found, 1);
        }
        __syncthreads();
        if (threadIdx.x == 0) *flag = (found == 0) ? 1 : 0;   // 1 => int64
        return;
    }
    int t = blockIdx.x * 256 + threadIdx.x;   // 16 x 256 = 4096 slots
    {
        int p  = t & 7;          // physical 16B slot
        int n  = (t >> 3) & 63;  // output column
        int kb = t >> 9;         // 64-wide k block, 0..7
        int l  = p ^ (n & 7);    // logical slot
        int k0 = kb * 64 + l * 8;
        unsigned short v[8];
#pragma unroll
        for (int j = 0; j < 8; j++) v[j] = f2b(W1[(size_t)(k0 + j) * HC1 + n]);
        *(uint4*)(wst + ((size_t)(kb * 64 + n) * 64 + p * 8)) = *(uint4*)v;
    }
    if (blockIdx.x == 0 && threadIdx.x < HC1) {
        int c = threadIdx.x;
        float s = 0.f, d = 0.f;
#pragma unroll
        for (int j = 0; j < NC; j++) {
            float w = W2[c * NC + j];
            s += w * a_s2[j];
            d += w * a_d2[j];
        }
        ws2[c] = s;
        wd2[c] = d;
    }
}

// ---------------- scatter pass 1: deg hist + bucket append (packed 4B records) -----
__global__ __launch_bounds__(256) void scatter1(const int* __restrict__ ei, const int* __restrict__ flag,
                                                int* __restrict__ deg, int* __restrict__ bcnt,
                                                int* __restrict__ bpk, int E, int NB) {
    __shared__ int cnt[MAXNB];
    __shared__ int gb[MAXNB];
    int tid = threadIdx.x;
    for (int i = tid; i < NB; i += 256) cnt[i] = 0;
    __syncthreads();
    int f = *flag;
    int base = blockIdx.x * RADIX_EPB;
    int pk[16], bk[16], rv[16];
#pragma unroll
    for (int i = 0; i < 16; i++) {
        int e = base + i * 256 + tid;
        if (e < E) {
            int s, d;
            if (f) { s = ei[2 * e]; d = ei[2 * (E + e)]; }
            else   { s = ei[e];     d = ei[E + e]; }
            pk[i] = (s << 8) | (d & 255);
            bk[i] = d >> 8;
            rv[i] = atomicAdd(&cnt[bk[i]], 1);
            atomicAdd(&deg[d], 1);
        }
    }
    __syncthreads();
    for (int i = tid; i < NB; i += 256) {
        int c = cnt[i];
        gb[i] = c ? atomicAdd(&bcnt[i], c) : 0;
    }
    __syncthreads();
#pragma unroll
    for (int i = 0; i < 16; i++) {
        int e = base + i * 256 + tid;
        if (e < E) {
            int pos = gb[bk[i]] + rv[i];
            if (pos < BCAP)
                bpk[(size_t)bk[i] * BCAP + pos] = pk[i];
        }
    }
}

// ---------------- CSR rowptr: scans ----------------
__global__ __launch_bounds__(256) void scan1(const int* __restrict__ deg, int* __restrict__ rowptr,
                                             int* __restrict__ bsums, int n) {
    __shared__ int sbuf[256];
    int tid = threadIdx.x;
    int base = blockIdx.x * SCAN_CHUNK + tid * 8;
    int v[8];
#pragma unroll
    for (int j = 0; j < 8; j++) { int idx = base + j; v[j] = (idx < n) ? deg[idx] : 0; }
    int tsum = 0;
#pragma unroll
    for (int j = 0; j < 8; j++) tsum += v[j];
    sbuf[tid] = tsum;
    __syncthreads();
    for (int off = 1; off < 256; off <<= 1) {
        int t = (tid >= off) ? sbuf[tid - off] : 0;
        __syncthreads();
        sbuf[tid] += t;
        __syncthreads();
    }
    int run = sbuf[tid] - tsum;
#pragma unroll
    for (int j = 0; j < 8; j++) {
        run += v[j];
        int idx = base + j;
        if (idx < n) rowptr[1 + idx] = run;
    }
    if (tid == 255) bsums[blockIdx.x] = sbuf[255];
}

__global__ __launch_bounds__(256) void scan23(int* __restrict__ rowptr,
                                              const int* __restrict__ bsums, int n, int nb) {
    __shared__ int soff[64];
    int tid = threadIdx.x;
    if (tid < 64) {
        int lane = tid;
        int v = (lane < nb) ? bsums[lane] : 0;
        int orig = v;
        for (int off = 1; off < 64; off <<= 1) {
            int t = __shfl_up(v, (unsigned)off, 64);
            if (lane >= off) v += t;
        }
        soff[lane] = v - orig;
    }
    __syncthreads();
    int i = blockIdx.x * 256 + tid;
    if (i < n) {
        rowptr[1 + i] += soff[i >> 11];
        if (i == 0) rowptr[0] = 0;
    }
}

// ---------------- scatter pass 2: per-bucket finalize (LDS cursors) ----------------
__global__ __launch_bounds__(256) void scatter2(const int* __restrict__ bpk,
                                                const int* __restrict__ bcnt,
                                                const int* __restrict__ rowptr,
                                                int* __restrict__ col, int Nn) {
    __shared__ int cur[256];
    int b = blockIdx.x;
    int node0 = b << 8;
    int tid = threadIdx.x;
    int nlast = min(node0 + 256, Nn);
    if (node0 + tid < nlast) cur[tid] = rowptr[node0 + tid];
    __syncthreads();
    int cnt = min(bcnt[b], BCAP);
    const int* bp = bpk + (size_t)b * BCAP;
    for (int j = tid; j < cnt; j += 256) {
        int pk = bp[j];
        int pos = atomicAdd(&cur[pk & 255], 1);
        col[pos] = (int)((unsigned)pk >> 8);
    }
}

// ---------------- GEMM1 (bf16 MFMA) + fused alpha1 ----------------
// Output layouts now SLICE-MAJOR for L2-resident gathers:
//   h1s[4][N][16] bf16 (slice s = channels 16s..16s+16)
//   as1s/ad1s[4][N][2] fp32 (slice s = heads 2s, 2s+1)
__global__ __launch_bounds__(256) void gemm1(const float* __restrict__ x,
                                             const unsigned short* __restrict__ wst,
                                             const float* __restrict__ a_s, const float* __restrict__ a_d,
                                             unsigned short* __restrict__ h1s, float* __restrict__ as1s,
                                             float* __restrict__ ad1s, int Nn) {
    __shared__ __align__(16) unsigned short smem[8192];   // xs[64][64] | ws[64][64]
    unsigned short* xs = smem;          // swizzled A tile
    unsigned short* ws = smem + 4096;   // swizzled B tile (image == wst tile)
    int tid = threadIdx.x;
    int m0 = blockIdx.x * 64;
    int w = tid >> 6, lane = tid & 63;
    int quad = lane >> 4, mr = lane & 15;
    f32x4 acc[4];
#pragma unroll
    for (int i = 0; i < 4; i++) acc[i] = (f32x4){0.f, 0.f, 0.f, 0.f};

    int srow = tid >> 2;        // 0..63 staged row
    int sseg = tid & 3;         // 16-float segment within 64-wide k chunk
    bool rok = (m0 + srow) < Nn;
    const float* xrow = x + (size_t)(m0 + srow) * F_IN + sseg * 16;
    int swzw = (srow & 7) << 4;             // write-side XOR (bytes)
    int swzr = (mr & 7) << 4;               // read-side XOR (bytes)

    for (int kb = 0; kb < 8; kb++) {
        float4 xv0, xv1, xv2, xv3;
        if (rok) {
            const float4* xp = (const float4*)(xrow + kb * 64);
            xv0 = xp[0]; xv1 = xp[1]; xv2 = xp[2]; xv3 = xp[3];
        } else {
            xv0 = xv1 = xv2 = xv3 = make_float4(0.f, 0.f, 0.f, 0.f);
        }
        const uint4* wp = (const uint4*)(wst + (size_t)kb * 4096);
        uint4 wv0 = wp[tid];
        uint4 wv1 = wp[tid + 256];
        __syncthreads();   // previous iteration's MFMA reads complete
        {
            unsigned short bx[16];
            bx[0]  = f2b(xv0.x); bx[1]  = f2b(xv0.y); bx[2]  = f2b(xv0.z); bx[3]  = f2b(xv0.w);
            bx[4]  = f2b(xv1.x); bx[5]  = f2b(xv1.y); bx[6]  = f2b(xv1.z); bx[7]  = f2b(xv1.w);
            bx[8]  = f2b(xv2.x); bx[9]  = f2b(xv2.y); bx[10] = f2b(xv2.z); bx[11] = f2b(xv2.w);
            bx[12] = f2b(xv3.x); bx[13] = f2b(xv3.y); bx[14] = f2b(xv3.z); bx[15] = f2b(xv3.w);
            unsigned short* xr = xs + srow * 64;
            *(uint4*)(xr + ((((sseg * 32)      ) ^ swzw) >> 1)) = *(uint4*)&bx[0];
            *(uint4*)(xr + ((((sseg * 32) + 16 ) ^ swzw) >> 1)) = *(uint4*)&bx[8];
            ((uint4*)ws)[tid]       = wv0;
            ((uint4*)ws)[tid + 256] = wv1;
        }
        __syncthreads();
#pragma unroll
        for (int ks = 0; ks < 2; ks++) {
            int kc = ks * 64 + quad * 16;           // logical byte col of fragment
            int co = (kc ^ swzr) >> 1;              // swizzled ushort offset
            bf16x8 a = *(const bf16x8*)(xs + (w * 16 + mr) * 64 + co);
#pragma unroll
            for (int nb = 0; nb < 4; nb++) {
                bf16x8 b = *(const bf16x8*)(ws + (nb * 16 + mr) * 64 + co);
                acc[nb] = __builtin_amdgcn_mfma_f32_16x16x32_bf16(a, b, acc[nb], 0, 0, 0);
            }
        }
    }
    __syncthreads();
    // D -> LDS tile (overlay hs[64][72] on smem)
    unsigned short (*hs)[72] = (unsigned short(*)[72])smem;
#pragma unroll
    for (int nb = 0; nb < 4; nb++)
#pragma unroll
        for (int r = 0; r < 4; r++)
            hs[w * 16 + quad * 4 + r][nb * 16 + mr] = f2b(acc[nb][r]);
    __syncthreads();
    // slice-major bf16 store: thread -> 32B (one node's 16-ch slice)
    {
        if (rok) {
            uint4 v0 = *(const uint4*)&hs[srow][sseg * 16];
            uint4 v1 = *(const uint4*)&hs[srow][sseg * 16 + 8];
            uint4* dst = (uint4*)(h1s + ((size_t)sseg * Nn + (m0 + srow)) * 16);
            dst[0] = v0;
            dst[1] = v1;
        }
    }
    // fused alpha1: 512 (row,head) pairs per block; slice-major stores
    for (int i = tid; i < 512; i += 256) {
        int row = i >> 3, hh = i & 7;
        if (m0 + row < Nn) {
            float s = 0.f, d = 0.f;
#pragma unroll
            for (int c = 0; c < 8; c++) {
                float v = b2f(hs[row][hh * 8 + c]);
                s += v * a_s[hh * 8 + c];
                d += v * a_d[hh * 8 + c];
            }
            size_t idx = ((size_t)(hh >> 1) * Nn + (m0 + row)) * 2 + (hh & 1);
            as1s[idx] = s;
            ad1s[idx] = d;
        }
    }
}

// ---------------- layer-1 aggregation: slice pass k (k=0..3) -----------------------
// Wave = one dst node. g = lane>>3 owns edge subgroup; cl = lane&7 owns 2 channels of
// the 16-ch slice; hl = cl>>2 is the head-local index (head 2k+hl).
// Gathers hit the 3.2 MB slice (per-XCD L2-resident). No LDS.
__global__ __launch_bounds__(256) void agg1p(const unsigned short* __restrict__ h1s,
                                             const float* __restrict__ as1s,
                                             const float* __restrict__ ad1s,
                                             const int* __restrict__ rowptr, const int* __restrict__ col,
                                             const float* __restrict__ b1,
                                             const float* __restrict__ ws2, const float* __restrict__ wd2,
                                             unsigned short* __restrict__ h2s, float* __restrict__ as2,
                                             float* __restrict__ ad2, int Nn, int k) {
    int wave = (blockIdx.x * 256 + threadIdx.x) >> 6;
    int lane = threadIdx.x & 63;
    if (wave >= Nn) return;
    int d = wave;
    int g = lane >> 3, cl = lane & 7;
    int hl = cl >> 2;                                        // head-local 0/1
    const unsigned short* hsl = h1s + (size_t)k * Nn * 16;
    const float* asl = as1s + (size_t)k * Nn * 2;
    const float* adl = ad1s + (size_t)k * Nn * 2;
    float adv = adl[(size_t)d * 2 + hl];
    float e0 = lrelu(asl[(size_t)d * 2 + hl] + adv);
    int jb = rowptr[d], je = rowptr[d + 1];
    float acc0 = 0.f, acc1 = 0.f, ss = 0.f;
    if (g == 0) {                                            // self-loop, p = 1
        unsigned gv = *(const unsigned*)(hsl + (size_t)d * 16 + 2 * cl);
        acc0 = b2f((unsigned short)(gv & 0xffff));
        acc1 = b2f((unsigned short)(gv >> 16));
        ss = 1.f;
    }
    for (int c = jb; c < je; c += 16) {                      // 16 edges/iter, 2/group
        int eA = c + g, eB = c + 8 + g;
        bool vA = eA < je, vB = eB < je;
        int sA = d, sB = d;
        if (vA) { unsigned u = (unsigned)col[eA]; sA = (u < (unsigned)Nn) ? (int)u : d; }
        if (vB) { unsigned u = (unsigned)col[eB]; sB = (u < (unsigned)Nn) ? (int)u : d; }
        float aA = asl[(size_t)sA * 2 + hl];
        float aB = asl[(size_t)sB * 2 + hl];
        unsigned gA = *(const unsigned*)(hsl + (size_t)sA * 16 + 2 * cl);
        unsigned gB = *(const unsigned*)(hsl + (size_t)sB * 16 + 2 * cl);
        float pA = vA ? __expf(lrelu(aA + adv) - e0) : 0.f;
        float pB = vB ? __expf(lrelu(aB + adv) - e0) : 0.f;
        acc0 += pA * b2f((unsigned short)(gA & 0xffff)) + pB * b2f((unsigned short)(gB & 0xffff));
        acc1 += pA * b2f((unsigned short)(gA >> 16))   + pB * b2f((unsigned short)(gB >> 16));
        ss += pA + pB;
    }
    // reduce across the 8 edge-groups (lane bits 3,4,5)
#pragma unroll
    for (int off = 8; off <= 32; off <<= 1) {
        acc0 += __shfl_xor(acc0, off, 64);
        acc1 += __shfl_xor(acc1, off, 64);
        ss   += __shfl_xor(ss, off, 64);
    }
    if (g == 0) {
        float inv = 1.f / (ss + 1e-16f);
        float o0 = acc0 * inv + b1[k * 16 + 2 * cl];
        float o1 = acc1 * inv + b1[k * 16 + 2 * cl + 1];
        o0 = o0 > 0.f ? o0 : __expf(o0) - 1.0f;              // ELU
        o1 = o1 > 0.f ? o1 : __expf(o1) - 1.0f;
        unsigned pk = (unsigned)f2h(o0) | ((unsigned)f2h(o1) << 16);
        *(unsigned*)(h2s + ((size_t)k * Nn + d) * 16 + 2 * cl) = pk;
        // partial as2/ad2 dot over this slice's 16 channels
        float va = o0 * ws2[k * 16 + 2 * cl] + o1 * ws2[k * 16 + 2 * cl + 1];
        float vd = o0 * wd2[k * 16 + 2 * cl] + o1 * wd2[k * 16 + 2 * cl + 1];
#pragma unroll
        for (int off = 1; off <= 4; off <<= 1) {             // reduce lanes 0..7
            va += __shfl_xor(va, off, 64);
            vd += __shfl_xor(vd, off, 64);
        }
        if (lane == 0) {
            if (k == 0) { as2[d] = va; ad2[d] = vd; }
            else        { atomicAdd(&as2[d], va); atomicAdd(&ad2[d], vd); }
        }
    }
}

// ---------------- layer-2 aggregation: slice pass k (k=0..3) -----------------------
// Single head: p is scalar per edge. Pass 0 also writes ssum2; hbar is UNnormalized.
__global__ __launch_bounds__(256) void agg2p(const unsigned short* __restrict__ h2s,
                                             const float* __restrict__ as2,
                                             const float* __restrict__ ad2,
                                             const int* __restrict__ rowptr, const int* __restrict__ col,
                                             float* __restrict__ hbar, float* __restrict__ ssum2,
                                             int Nn, int k) {
    int wave = (blockIdx.x * 256 + threadIdx.x) >> 6;
    int lane = threadIdx.x & 63;
    if (wave >= Nn) return;
    int d = wave;
    int g = lane >> 3, cl = lane & 7;
    const unsigned short* hsl = h2s + (size_t)k * Nn * 16;
    float adv = ad2[d];
    float e0 = lrelu(as2[d] + adv);
    int jb = rowptr[d], je = rowptr[d + 1];
    float acc0 = 0.f, acc1 = 0.f, ss = 0.f;
    if (g == 0) {                                            // self-loop, p = 1
        unsigned gv = *(const unsigned*)(hsl + (size_t)d * 16 + 2 * cl);
        acc0 = h2f((unsigned short)(gv & 0xffff));
        acc1 = h2f((unsigned short)(gv >> 16));
        ss = 1.f;
    }
    for (int c = jb; c < je; c += 16) {
        int eA = c + g, eB = c + 8 + g;
        bool vA = eA < je, vB = eB < je;
        int sA = d, sB = d;
        if (vA) { unsigned u = (unsigned)col[eA]; sA = (u < (unsigned)Nn) ? (int)u : d; }
        if (vB) { unsigned u = (unsigned)col[eB]; sB = (u < (unsigned)Nn) ? (int)u : d; }
        float aA = as2[sA];
        float aB = as2[sB];
        unsigned gA = *(const unsigned*)(hsl + (size_t)sA * 16 + 2 * cl);
        unsigned gB = *(const unsigned*)(hsl + (size_t)sB * 16 + 2 * cl);
        float pA = vA ? __expf(lrelu(aA + adv) - e0) : 0.f;
        float pB = vB ? __expf(lrelu(aB + adv) - e0) : 0.f;
        acc0 += pA * h2f((unsigned short)(gA & 0xffff)) + pB * h2f((unsigned short)(gB & 0xffff));
        acc1 += pA * h2f((unsigned short)(gA >> 16))   + pB * h2f((unsigned short)(gB >> 16));
        ss += pA + pB;
    }
#pragma unroll
    for (int off = 8; off <= 32; off <<= 1) {
        acc0 += __shfl_xor(acc0, off, 64);
        acc1 += __shfl_xor(acc1, off, 64);
        ss   += __shfl_xor(ss, off, 64);
    }
    if (g == 0) {
        *(float2*)(hbar + ((size_t)k * Nn + d) * 16 + 2 * cl) = make_float2(acc0, acc1);
        if (k == 0 && cl == 0) ssum2[d] = ss;
    }
}

// ---------------- final: normalize + W2 matvec + bias + log_softmax ----------------
__global__ __launch_bounds__(256) void fin(const float* __restrict__ hbar,
                                           const float* __restrict__ ssum2,
                                           const float* __restrict__ W2, const float* __restrict__ b2,
                                           float* __restrict__ out, int Nn) {
    __shared__ float W2s[HC1 * NC];
    __shared__ float hv[4][HC1];
    int tid = threadIdx.x;
    for (int i = tid; i < HC1 * NC; i += 256) W2s[i] = W2[i];
    __syncthreads();
    int w = tid >> 6;
    int wave = (blockIdx.x * 256 + tid) >> 6;
    int lane = tid & 63;
    if (wave >= Nn) return;
    int d = wave;
    // lane = k*16 + j loads hbar slice k, channel j (original channel order)
    hv[w][lane] = hbar[((size_t)(lane >> 4) * Nn + d) * 16 + (lane & 15)];
    float inv = 1.f / (ssum2[d] + 1e-16f);
    float o = 0.f;
    if (lane < NC) {
        float dot = 0.f;
        const float* sv = hv[w];                 // same-wave produce->consume
#pragma unroll
        for (int c = 0; c < HC1; c++) dot += sv[c] * W2s[c * NC + lane];
        o = b2[lane] + inv * dot;
    }
    float vm = (lane < NC) ? o : -1e30f;
#pragma unroll
    for (int off = 32; off; off >>= 1) vm = fmaxf(vm, __shfl_xor(vm, off, 64));
    float ex = (lane < NC) ? __expf(o - vm) : 0.f;
#pragma unroll
    for (int off = 32; off; off >>= 1) ex += __shfl_xor(ex, off, 64);
    float lsm = o - vm - __logf(ex);
    if (lane < NC) out[(size_t)d * NC + lane] = lsm;
}

// ---------------- host launch ----------------
extern "C" void kernel_launch(void* const* d_in, const int* in_sizes, int n_in,
                              void* d_out, int out_size, void* d_ws, size_t ws_size,
                              hipStream_t stream) {
    const float* x      = (const float*)d_in[0];
    const int*   ei     = (const int*)d_in[1];
    const float* W1     = (const float*)d_in[2];
    const float* a_src1 = (const float*)d_in[3];
    const float* a_dst1 = (const float*)d_in[4];
    const float* b1     = (const float*)d_in[5];
    const float* W2     = (const float*)d_in[6];
    const float* a_src2 = (const float*)d_in[7];
    const float* a_dst2 = (const float*)d_in[8];
    const float* b2     = (const float*)d_in[9];
    float* out = (float*)d_out;

    const int N = in_sizes[0] / F_IN;       // 100000
    const int E = in_sizes[1] / 2;          // 1600000
    const int NB = (N + 255) >> 8;          // 256-node buckets (391)

    char* p = (char*)d_ws;
    auto alloc = [&](size_t bytes) -> void* {
        void* r = (void*)p;
        p += (bytes + 255) & ~(size_t)255;
        return r;
    };
    int* deg    = (int*)alloc((size_t)N * 4);
    int* bcnt   = (int*)alloc((size_t)MAXNB * 4);      // adjacent to deg: one memset
    int* rowptr = (int*)alloc(((size_t)N + 1) * 4);
    int* bsums  = (int*)alloc(64 * 4);
    int* flag   = (int*)alloc(256);
    int* bpk    = (int*)alloc((size_t)NB * BCAP * 4);                   // 12.8 MB packed
    int* col    = (int*)alloc((size_t)E * 4);
    unsigned short* h1s = (unsigned short*)alloc((size_t)4 * N * 16 * 2);  // bf16 slices
    float* as1s = (float*)alloc((size_t)4 * N * 2 * 4);
    float* ad1s = (float*)alloc((size_t)4 * N * 2 * 4);
    unsigned short* h2s = (unsigned short*)alloc((size_t)4 * N * 16 * 2);  // fp16 slices
    float* as2  = (float*)alloc((size_t)N * 4);
    float* ad2  = (float*)alloc((size_t)N * 4);
    float* ssum2 = (float*)alloc((size_t)N * 4);
    float* hbar = (float*)alloc((size_t)4 * N * 16 * 4);                // fp32 slices
    unsigned short* wst = (unsigned short*)alloc(8 * 64 * 64 * 2);      // 64KB, swizzled bf16 W1
    float* ws2  = (float*)alloc(HC1 * 4);
    float* wd2  = (float*)alloc(HC1 * 4);

    // --- CSR build + param prep ---
    size_t zlen = (size_t)((char*)(bcnt + MAXNB) - (char*)deg);
    hipMemsetAsync(deg, 0, zlen, stream);
    prep<<<17, 256, 0, stream>>>(W1, W2, a_src2, a_dst2, ei, wst, ws2, wd2, flag);
    scatter1<<<(E + RADIX_EPB - 1) / RADIX_EPB, 256, 0, stream>>>(ei, flag, deg, bcnt, bpk, E, NB);
    int nb = (N + SCAN_CHUNK - 1) / SCAN_CHUNK;
    scan1<<<nb, 256, 0, stream>>>(deg, rowptr, bsums, N);
    scan23<<<(N + 255) / 256, 256, 0, stream>>>(rowptr, bsums, N, nb);
    scatter2<<<NB, 256, 0, stream>>>(bpk, bcnt, rowptr, col, N);

    // --- layer 1 ---
    gemm1<<<(N + 63) / 64, 256, 0, stream>>>(x, wst, a_src1, a_dst1, h1s, as1s, ad1s, N);
    int gagg = (N + 3) / 4;
    for (int k = 0; k < 4; k++)
        agg1p<<<gagg, 256, 0, stream>>>(h1s, as1s, ad1s, rowptr, col, b1, ws2, wd2,
                                        h2s, as2, ad2, N, k);

    // --- layer 2 ---
    for (int k = 0; k < 4; k++)
        agg2p<<<gagg, 256, 0, stream>>>(h2s, as2, ad2, rowptr, col, hbar, ssum2, N, k);
    fin<<<gagg, 256, 0, stream>>>(hbar, ssum2, W2, b2, out, N);
}